// Round 16
// baseline (419.930 us; speedup 1.0000x reference)
//
#include <hip/hip_runtime.h>
#include <hip/hip_bf16.h>
#include <cstdint>
#include <cstddef>

#define D_DIM 2048
#define L_SEQ 2048
#define B_SZ 4
#define M_ROWS (B_SZ * L_SEQ)   /* 8192 */
#define NT_COLS (3 * D_DIM)     /* 6144: seg0=A, seg1=dt, seg2=rawB */
#define NCH 16
#define CHUNK (L_SEQ / NCH)     /* 128 */

typedef __bf16 bf16_t;
typedef bf16_t bf16x8 __attribute__((ext_vector_type(8)));
typedef float f32x4 __attribute__((ext_vector_type(4)));

__device__ __forceinline__ void gl_lds16(const void* g, void* l) {
    __builtin_amdgcn_global_load_lds(
        (const __attribute__((address_space(1))) unsigned int*)g,
        (__attribute__((address_space(3))) unsigned int*)l, 16, 0, 0);
}

#define BAR()    asm volatile("s_barrier" ::: "memory")
#define VMCNT0() asm volatile("s_waitcnt vmcnt(0)" ::: "memory")

// ---------------- convert force f32 -> bf16 (16B stores) ----------------
__global__ __launch_bounds__(256) void cvt_bf16_kernel(
    const float* __restrict__ in, bf16_t* __restrict__ out, int n8)
{
    int i = blockIdx.x * 256 + threadIdx.x;
    if (i >= n8) return;
    float4 f0 = ((const float4*)in)[2 * i];
    float4 f1 = ((const float4*)in)[2 * i + 1];
    bf16x8 o;
    o[0] = (bf16_t)f0.x; o[1] = (bf16_t)f0.y; o[2] = (bf16_t)f0.z; o[3] = (bf16_t)f0.w;
    o[4] = (bf16_t)f1.x; o[5] = (bf16_t)f1.y; o[6] = (bf16_t)f1.z; o[7] = (bf16_t)f1.w;
    ((bf16x8*)out)[i] = o;
}

// ------- transpose W[k][j] -> Wt[j][k] with f32->bf16; z picks matrix -------
__global__ __launch_bounds__(256) void transpose_w_kernel(
    const float* __restrict__ W0, const float* __restrict__ W1,
    const float* __restrict__ W2, bf16_t* __restrict__ Wt)
{
    __shared__ float tile[32][33];
    const float* W = (blockIdx.z == 0) ? W0 : (blockIdx.z == 1) ? W1 : W2;
    bf16_t* dst = Wt + (size_t)blockIdx.z * D_DIM * D_DIM;
    int j0 = blockIdx.x * 32, k0 = blockIdx.y * 32;
    int tx = threadIdx.x, ty = threadIdx.y;      // block (32, 8)
#pragma unroll
    for (int i = 0; i < 4; i++) {
        int k = k0 + ty + i * 8;
        tile[ty + i * 8][tx] = W[(size_t)k * D_DIM + j0 + tx];
    }
    __syncthreads();
#pragma unroll
    for (int i = 0; i < 4; i++) {
        int j = j0 + ty + i * 8;
        dst[(size_t)j * D_DIM + k0 + tx] = (bf16_t)tile[tx][ty + i * 8];
    }
}

// ---------------- fused bf16 GEMM: [8192 x 2048] @ [2048 x 6144] ----------------
// 256x256 tile, BK=64, 16 waves (4m x 4n, wave owns 64x64 — R13's proven
// per-wave shape, acc[4][4]), 2-phase double-buffer, one vmcnt(0)+barrier
// per K-tile. Scale-up of the R12 session-best skeleton: drain events per
// unit work halve (1 block x 32 tiles vs 2 x 32), B refetch halves.
// LDS 128KB -> 1 block/CU x 16 waves = same 4 waves/SIMD as R12.
// Verified 0-conflict swizzle pair (R7/R8/R12):
//   stage: LDS dest linear, global col slot ^= (row&7)
//   read : slot = (ks*4 + (lane>>4)) ^ (frow&7)
// Ledger (do not revisit): structure changes 0-for-6 (R2/R3/R9/R10/R11/R14);
// R5: bf16 epilogue stores -> acc spill (keep f32); R9: 32x32 MFMA frag
// reads conflict 2.5e7 (keep 16x16). 2-phase wall (m233) binds at ~650 TF.
#define STAGE(LA, LB, T) {                                                     \
    const size_t kofs_ = (size_t)(T) * 64;                                     \
    _Pragma("unroll") for (int j = 0; j < 2; j++) {                            \
        gl_lds16(gA[j] + kofs_, (LA) + j * 8192 + w * 512);                    \
        gl_lds16(gB[j] + kofs_, (LB) + j * 8192 + w * 512);                    \
    } }

#define COMPUTE(LA, LB) {                                                      \
    bf16x8 af[4], bfr[4];                                                      \
    _Pragma("unroll") for (int m = 0; m < 4; m++)                              \
        af[m] = *(const bf16x8*)&(LA)[(wr + m * 16) * 64 + lof0];              \
    _Pragma("unroll") for (int n = 0; n < 4; n++)                              \
        bfr[n] = *(const bf16x8*)&(LB)[(wc + n * 16) * 64 + lof0];             \
    __builtin_amdgcn_s_setprio(1);                                             \
    _Pragma("unroll") for (int m = 0; m < 4; m++)                              \
        _Pragma("unroll") for (int n = 0; n < 4; n++)                          \
            acc[m][n] = __builtin_amdgcn_mfma_f32_16x16x32_bf16(               \
                af[m], bfr[n], acc[m][n], 0, 0, 0);                            \
    __builtin_amdgcn_s_setprio(0);                                             \
    _Pragma("unroll") for (int m = 0; m < 4; m++)                              \
        af[m] = *(const bf16x8*)&(LA)[(wr + m * 16) * 64 + lof1];              \
    _Pragma("unroll") for (int n = 0; n < 4; n++)                              \
        bfr[n] = *(const bf16x8*)&(LB)[(wc + n * 16) * 64 + lof1];             \
    __builtin_amdgcn_s_setprio(1);                                             \
    _Pragma("unroll") for (int m = 0; m < 4; m++)                              \
        _Pragma("unroll") for (int n = 0; n < 4; n++)                          \
            acc[m][n] = __builtin_amdgcn_mfma_f32_16x16x32_bf16(               \
                af[m], bfr[n], acc[m][n], 0, 0, 0);                            \
    __builtin_amdgcn_s_setprio(0);                                             \
}

__global__ __launch_bounds__(1024) void gemm_fused_kernel(
    const bf16_t* __restrict__ Abf,   // force bf16 [8192][2048]
    const bf16_t* __restrict__ Wt,    // [6144][2048] (W^T, concat A|dt|B)
    const float* __restrict__ bA, const float* __restrict__ bdt,
    const float* __restrict__ bB, const float* __restrict__ scales,
    float* __restrict__ outA,         // -> d_out x-region (staging)
    float* __restrict__ outDT,        // -> ws
    float* __restrict__ outB)         // -> d_out v-region (staging)
{
    __shared__ bf16_t lds_a0[256 * 64];   // 32 KB
    __shared__ bf16_t lds_a1[256 * 64];
    __shared__ bf16_t lds_b0[256 * 64];
    __shared__ bf16_t lds_b1[256 * 64];   // total 128 KB

    const int bm0 = blockIdx.x * 256;         // M block (fastest)
    const int bn0 = blockIdx.y * 256;         // NT block
    const int t = threadIdx.x;                // 0..1023
    const int lane = t & 63, w = t >> 6;      // 16 waves
    const int wr = (w >> 2) * 64;             // 4 m-groups
    const int wc = (w & 3) * 64;              // 4 n-groups

    f32x4 acc[4][4] = {};

    // staging: thread covers rows (t>>3) and (t>>3)+128; linear 16B slot t&7,
    // global col pre-swizzled slot ^ (row&7) = (t&7) ^ ((t>>3)&7).
    const int srow = t >> 3;                  // 0..127
    const int scol = (((t & 7) ^ ((t >> 3) & 7)) << 3);   // elements
    const bf16_t* gA[2];
    const bf16_t* gB[2];
#pragma unroll
    for (int j = 0; j < 2; j++) {
        gA[j] = Abf + (size_t)(bm0 + j * 128 + srow) * D_DIM + scol;
        gB[j] = Wt + (size_t)(bn0 + j * 128 + srow) * D_DIM + scol;
    }

    // frag reads (verified 0-conflict): row = frow in 16-row group
    const int frow = lane & 15;
    const int q = lane >> 4;
    const int fx7 = frow & 7;
    const int lof0 = frow * 64 + (((q) ^ fx7) << 3);          // ks=0, elems
    const int lof1 = frow * 64 + (((4 + q) ^ fx7) << 3);      // ks=1, elems

    // prologue: tile 0 into buf0
    STAGE(lds_a0, lds_b0, 0);
    VMCNT0();
    BAR();

    // main loop: 15 iters x 2 K-tiles (computes tiles 0..29), static ping-pong
#pragma unroll 1
    for (int i = 0; i < 15; ++i) {
        const int tt = 2 * i;
        STAGE(lds_a1, lds_b1, tt + 1);
        COMPUTE(lds_a0, lds_b0);
        VMCNT0();
        BAR();
        STAGE(lds_a0, lds_b0, tt + 2);
        COMPUTE(lds_a1, lds_b1);
        VMCNT0();
        BAR();
    }
    // tail: stage 31 -> buf1; compute 30 (buf0); compute 31 (buf1)
    STAGE(lds_a1, lds_b1, 31);
    COMPUTE(lds_a0, lds_b0);
    VMCNT0();
    BAR();
    COMPUTE(lds_a1, lds_b1);

    // epilogue: C/D layout col = lane&15, row = (lane>>4)*4 + reg  [m89-verified]
    const int seg = bn0 >> 11;                        // 0=A, 1=dt, 2=rawB
    const int dbase = (bn0 & 2047) + wc + (lane & 15);
    const int rowbase = bm0 + wr + (q << 2);

    if (seg == 0) {
        float bias[4];
#pragma unroll
        for (int n = 0; n < 4; n++) bias[n] = bA[dbase + n * 16];
#pragma unroll
        for (int m = 0; m < 4; m++)
#pragma unroll
            for (int n = 0; n < 4; n++)
#pragma unroll
                for (int r = 0; r < 4; r++) {
                    size_t idx = (size_t)(rowbase + m * 16 + r) * D_DIM + dbase + n * 16;
                    outA[idx] = 1.0f / (1.0f + __expf(-(acc[m][n][r] + bias[n])));
                }
    } else if (seg == 1) {
        float bias[4], sc[4];
#pragma unroll
        for (int n = 0; n < 4; n++) { bias[n] = bdt[dbase + n * 16]; sc[n] = scales[dbase + n * 16]; }
#pragma unroll
        for (int m = 0; m < 4; m++)
#pragma unroll
            for (int n = 0; n < 4; n++)
#pragma unroll
                for (int r = 0; r < 4; r++) {
                    size_t idx = (size_t)(rowbase + m * 16 + r) * D_DIM + dbase + n * 16;
                    float xx = acc[m][n][r] + bias[n];
                    float sp = xx > 0.f ? xx + log1pf(__expf(-xx)) : log1pf(__expf(xx));
                    outDT[idx] = sp * 0.1f * sc[n];
                }
    } else {
        float bias[4];
#pragma unroll
        for (int n = 0; n < 4; n++) bias[n] = bB[dbase + n * 16];
#pragma unroll
        for (int m = 0; m < 4; m++)
#pragma unroll
            for (int n = 0; n < 4; n++)
#pragma unroll
                for (int r = 0; r < 4; r++) {
                    size_t idx = (size_t)(rowbase + m * 16 + r) * D_DIM + dbase + n * 16;
                    outB[idx] = acc[m][n][r] + bias[n];
                }
    }
}

// ---------------- scan pass 1: per-chunk affine aggregates ----------------
// step map: v' = a v + bv ; x' = x + dt v'  =>  (P,R,U,W):
//   v_out = P v + U ; x_out = R v + x + W
// 2 adjacent d-channels per thread (float2 loads).
__global__ __launch_bounds__(256) void scan_pass1_kernel(
    const float* __restrict__ Aarr, const float* __restrict__ Braw,
    const float* __restrict__ dtv, float4* __restrict__ agg)
{
    int pp = blockIdx.x * 256 + threadIdx.x;    // 65536 pair-threads
    int dp = (pp & 1023) << 1;                  // d pair base
    int c = (pp >> 10) & (NCH - 1);
    int b = pp >> 14;
    size_t base = ((size_t)(b * L_SEQ + c * CHUNK)) * D_DIM + dp;
    float P0 = 1.f, R0 = 0.f, U0 = 0.f, W0 = 0.f;
    float P1 = 1.f, R1 = 0.f, U1 = 0.f, W1 = 0.f;
#pragma unroll 4
    for (int tt = 0; tt < CHUNK; tt++) {
        size_t idx = base + (size_t)tt * D_DIM;
        float2 a2  = *(const float2*)&Aarr[idx];
        float2 rb2 = *(const float2*)&Braw[idx];
        float2 dt2 = *(const float2*)&dtv[idx];
        float bv0 = rb2.x * dt2.x, bv1 = rb2.y * dt2.y;
        float da0 = dt2.x * a2.x,  da1 = dt2.y * a2.y;
        R0 = da0 * P0 + R0;  W0 = da0 * U0 + dt2.x * bv0 + W0;
        U0 = a2.x * U0 + bv0;  P0 = a2.x * P0;
        R1 = da1 * P1 + R1;  W1 = da1 * U1 + dt2.y * bv1 + W1;
        U1 = a2.y * U1 + bv1;  P1 = a2.y * P1;
    }
    int ch = ((b * NCH + c) << 11) + dp;
    agg[ch]     = make_float4(P0, R0, U0, W0);
    agg[ch + 1] = make_float4(P1, R1, U1, W1);
}

// ---------------- scan pass 2: combine chunk aggregates ----------------
__global__ __launch_bounds__(256) void scan_pass2_kernel(
    const float4* __restrict__ agg, float2* __restrict__ pre)
{
    int tid = blockIdx.x * 256 + threadIdx.x;   // 8192 channels
    int d = tid & (D_DIM - 1);
    int b = tid >> 11;
    float v = 0.f, x = 0.f;
#pragma unroll
    for (int c = 0; c < NCH; c++) {
        int i = ((b * NCH + c) << 11) + d;
        float4 g = agg[i];
        pre[i] = make_float2(v, x);             // state entering chunk c
        float vn = g.x * v + g.z;
        x = g.y * v + x + g.w;                  // uses old v
        v = vn;
    }
}

// ---------------- scan pass 3: replay chunk, write outputs in place ----------------
// A staged in xout, rawB staged in vout; overwritten in place
// (read-before-write, same element, same thread).
__global__ __launch_bounds__(256) void scan_pass3_kernel(
    const float* __restrict__ dtv, const float2* __restrict__ pre,
    float* __restrict__ xout, float* __restrict__ vout)
{
    int pp = blockIdx.x * 256 + threadIdx.x;    // 65536 pair-threads
    int dp = (pp & 1023) << 1;
    int c = (pp >> 10) & (NCH - 1);
    int b = pp >> 14;
    int ch = ((b * NCH + c) << 11) + dp;
    float4 pv = *(const float4*)&pre[ch];       // {v0,x0,v1,x1}
    float v0 = pv.x, x0 = pv.y, v1 = pv.z, x1 = pv.w;
    size_t base = ((size_t)(b * L_SEQ + c * CHUNK)) * D_DIM + dp;
#pragma unroll 4
    for (int tt = 0; tt < CHUNK; tt++) {
        size_t idx = base + (size_t)tt * D_DIM;
        float2 a2  = *(const float2*)&xout[idx];   // A (staged)
        float2 rb2 = *(const float2*)&vout[idx];   // rawB (staged)
        float2 dt2 = *(const float2*)&dtv[idx];
        v0 = a2.x * v0 + rb2.x * dt2.x;
        x0 = x0 + v0 * dt2.x;
        v1 = a2.y * v1 + rb2.y * dt2.y;
        x1 = x1 + v1 * dt2.y;
        *(float2*)&vout[idx] = make_float2(v0, v1);
        *(float2*)&xout[idx] = make_float2(x0, x1);
    }
}

extern "C" void kernel_launch(void* const* d_in, const int* in_sizes, int n_in,
                              void* d_out, int out_size, void* d_ws, size_t ws_size,
                              hipStream_t stream) {
    // inputs: 0:x 1:v 2:force 3:WA 4:bA 5:WB 6:bB 7:Wdt 8:bdt 9:scales
    const float* force  = (const float*)d_in[2];
    const float* WA     = (const float*)d_in[3];
    const float* bA     = (const float*)d_in[4];
    const float* WB     = (const float*)d_in[5];
    const float* bB     = (const float*)d_in[6];
    const float* Wdt    = (const float*)d_in[7];
    const float* bdt    = (const float*)d_in[8];
    const float* scales = (const float*)d_in[9];

    float* xout = (float*)d_out;                          // x_seq [8192*2048]
    float* vout = xout + (size_t)M_ROWS * D_DIM;          // v_seq

    // ws layout (123 MiB): R1 layout
    char* ws = (char*)d_ws;
    bf16_t* fbf = (bf16_t*)ws;                                     // 32 MB
    bf16_t* wt  = (bf16_t*)(ws + (size_t)33554432);                // 24 MB
    float*  dtv = (float*)(ws + (size_t)33554432 + 25165824);      // 64 MB
    float4* agg = (float4*)(ws + (size_t)33554432 + 25165824 + 67108864); // 2 MB
    float2* pre = (float2*)(ws + (size_t)33554432 + 25165824 + 67108864 + 2097152); // 1 MB

    // 1) force -> bf16
    {
        int n8 = M_ROWS * D_DIM / 8;
        cvt_bf16_kernel<<<n8 / 256, 256, 0, stream>>>(force, fbf, n8);
    }
    // 2) transpose + convert weights into concat [6144][2048]: A | dt | B
    {
        dim3 grid(D_DIM / 32, D_DIM / 32, 3), block(32, 8);
        transpose_w_kernel<<<grid, block, 0, stream>>>(WA, Wdt, WB, wt);
    }
    // 3) fused GEMM + activations (256^2 tile, BK=64, 2-phase, 16 waves)
    {
        dim3 grid(M_ROWS / 256, NT_COLS / 256);   // (32, 24)
        gemm_fused_kernel<<<grid, 1024, 0, stream>>>(fbf, wt, bA, bdt, bB, scales,
                                                     xout, dtv, vout);
    }
    // 4-6) chunked associative scan (2 channels per thread)
    scan_pass1_kernel<<<(B_SZ * NCH * D_DIM / 2) / 256, 256, 0, stream>>>(xout, vout, dtv, agg);
    scan_pass2_kernel<<<(B_SZ * D_DIM) / 256, 256, 0, stream>>>(agg, pre);
    scan_pass3_kernel<<<(B_SZ * NCH * D_DIM / 2) / 256, 256, 0, stream>>>(dtv, pre, xout, vout);
}

// Round 17
// 418.240 us; speedup vs baseline: 1.0040x; 1.0040x over previous
//
#include <hip/hip_runtime.h>
#include <hip/hip_bf16.h>
#include <cstdint>
#include <cstddef>

#define D_DIM 2048
#define L_SEQ 2048
#define B_SZ 4
#define M_ROWS (B_SZ * L_SEQ)   /* 8192 */
#define NT_COLS (3 * D_DIM)     /* 6144: seg0=A, seg1=dt, seg2=rawB */
#define NCH 16
#define CHUNK (L_SEQ / NCH)     /* 128 */

typedef __bf16 bf16_t;
typedef bf16_t bf16x8 __attribute__((ext_vector_type(8)));
typedef float f32x4 __attribute__((ext_vector_type(4)));

__device__ __forceinline__ void gl_lds16(const void* g, void* l) {
    __builtin_amdgcn_global_load_lds(
        (const __attribute__((address_space(1))) unsigned int*)g,
        (__attribute__((address_space(3))) unsigned int*)l, 16, 0, 0);
}

#define BAR()    asm volatile("s_barrier" ::: "memory")
#define VMCNT0() asm volatile("s_waitcnt vmcnt(0)" ::: "memory")

// ---------------- convert force f32 -> bf16 (16B stores) ----------------
__global__ __launch_bounds__(256) void cvt_bf16_kernel(
    const float* __restrict__ in, bf16_t* __restrict__ out, int n8)
{
    int i = blockIdx.x * 256 + threadIdx.x;
    if (i >= n8) return;
    float4 f0 = ((const float4*)in)[2 * i];
    float4 f1 = ((const float4*)in)[2 * i + 1];
    bf16x8 o;
    o[0] = (bf16_t)f0.x; o[1] = (bf16_t)f0.y; o[2] = (bf16_t)f0.z; o[3] = (bf16_t)f0.w;
    o[4] = (bf16_t)f1.x; o[5] = (bf16_t)f1.y; o[6] = (bf16_t)f1.z; o[7] = (bf16_t)f1.w;
    ((bf16x8*)out)[i] = o;
}

// ------- transpose W[k][j] -> Wt[j][k] with f32->bf16; z picks matrix -------
__global__ __launch_bounds__(256) void transpose_w_kernel(
    const float* __restrict__ W0, const float* __restrict__ W1,
    const float* __restrict__ W2, bf16_t* __restrict__ Wt)
{
    __shared__ float tile[32][33];
    const float* W = (blockIdx.z == 0) ? W0 : (blockIdx.z == 1) ? W1 : W2;
    bf16_t* dst = Wt + (size_t)blockIdx.z * D_DIM * D_DIM;
    int j0 = blockIdx.x * 32, k0 = blockIdx.y * 32;
    int tx = threadIdx.x, ty = threadIdx.y;      // block (32, 8)
#pragma unroll
    for (int i = 0; i < 4; i++) {
        int k = k0 + ty + i * 8;
        tile[ty + i * 8][tx] = W[(size_t)k * D_DIM + j0 + tx];
    }
    __syncthreads();
#pragma unroll
    for (int i = 0; i < 4; i++) {
        int j = j0 + ty + i * 8;
        dst[(size_t)j * D_DIM + k0 + tx] = (bf16_t)tile[tx][ty + i * 8];
    }
}

// ---------------- fused bf16 GEMM: [8192 x 2048] @ [2048 x 6144] ----------------
// R12/R15 configuration — best-TOTAL config (gemm ~319-327us, total 407.5us,
// reproduced twice). 128^2 tile, BK=64, 8 waves (2m x 4n), 2-phase double-
// buffer, one vmcnt(0)+barrier per K-tile. 16x16x32 MFMA.
// Verified 0-conflict swizzle pair (R7/R8/R12):
//   stage: LDS dest linear, global col slot ^= (row&7)
//   read : slot = (ks*4 + (lane>>4)) ^ (frow&7)
// Ledger (do not revisit): structure changes 0-for-6 (R2/R3/R9/R10/R11/R14).
// R16: 256^2 tile made the GEMM faster (305us) but total SLOWER (420us) —
// larger per-block output flush (WRITE 203->234MB) evicts the scan's inputs
// from L3; GEMM and scan are cache-coupled. Keep 128^2.
// R5: bf16 epilogue stores -> acc spill (keep f32). R9: 32x32 MFMA frag
// reads conflict 2.5e7 (keep 16x16). 2-phase wall (m233) binds at ~650 TF.
#define STAGE(LA, LB, T) {                                                     \
    const size_t kofs_ = (size_t)(T) * 64;                                     \
    _Pragma("unroll") for (int j = 0; j < 2; j++) {                            \
        gl_lds16(gA[j] + kofs_, (LA) + j * 4096 + w * 512);                    \
        gl_lds16(gB[j] + kofs_, (LB) + j * 4096 + w * 512);                    \
    } }

#define COMPUTE(LA, LB) {                                                      \
    bf16x8 af[4], bfr[2];                                                      \
    _Pragma("unroll") for (int m = 0; m < 4; m++)                              \
        af[m] = *(const bf16x8*)&(LA)[(wr + m * 16) * 64 + lof0];              \
    _Pragma("unroll") for (int n = 0; n < 2; n++)                              \
        bfr[n] = *(const bf16x8*)&(LB)[(wc + n * 16) * 64 + lof0];             \
    __builtin_amdgcn_s_setprio(1);                                             \
    _Pragma("unroll") for (int m = 0; m < 4; m++)                              \
        _Pragma("unroll") for (int n = 0; n < 2; n++)                          \
            acc[m][n] = __builtin_amdgcn_mfma_f32_16x16x32_bf16(               \
                af[m], bfr[n], acc[m][n], 0, 0, 0);                            \
    __builtin_amdgcn_s_setprio(0);                                             \
    _Pragma("unroll") for (int m = 0; m < 4; m++)                              \
        af[m] = *(const bf16x8*)&(LA)[(wr + m * 16) * 64 + lof1];              \
    _Pragma("unroll") for (int n = 0; n < 2; n++)                              \
        bfr[n] = *(const bf16x8*)&(LB)[(wc + n * 16) * 64 + lof1];             \
    __builtin_amdgcn_s_setprio(1);                                             \
    _Pragma("unroll") for (int m = 0; m < 4; m++)                              \
        _Pragma("unroll") for (int n = 0; n < 2; n++)                          \
            acc[m][n] = __builtin_amdgcn_mfma_f32_16x16x32_bf16(               \
                af[m], bfr[n], acc[m][n], 0, 0, 0);                            \
    __builtin_amdgcn_s_setprio(0);                                             \
}

__global__ __launch_bounds__(512) void gemm_fused_kernel(
    const bf16_t* __restrict__ Abf,   // force bf16 [8192][2048]
    const bf16_t* __restrict__ Wt,    // [6144][2048] (W^T, concat A|dt|B)
    const float* __restrict__ bA, const float* __restrict__ bdt,
    const float* __restrict__ bB, const float* __restrict__ scales,
    float* __restrict__ outA,         // -> d_out x-region (staging)
    float* __restrict__ outDT,        // -> ws
    float* __restrict__ outB)         // -> d_out v-region (staging)
{
    __shared__ bf16_t lds_a0[128 * 64];   // 16 KB
    __shared__ bf16_t lds_a1[128 * 64];
    __shared__ bf16_t lds_b0[128 * 64];
    __shared__ bf16_t lds_b1[128 * 64];   // total 64 KB

    const int bm0 = blockIdx.x * 128;         // M block (fastest)
    const int bn0 = blockIdx.y * 128;         // NT block
    const int t = threadIdx.x;                // 0..511
    const int lane = t & 63, w = t >> 6;      // 8 waves
    const int wr = (w >> 2) * 64;             // 2 m-groups
    const int wc = (w & 3) * 32;              // 4 n-groups

    f32x4 acc[4][2] = {};

    // staging: issue j covers rows j*64 + (t>>3); linear 16B slot t&7,
    // global col pre-swizzled slot ^ (row&7) = (t&7) ^ ((t>>3)&7).
    const int srow = t >> 3;                  // 0..63
    const int scol = (((t & 7) ^ ((t >> 3) & 7)) << 3);   // elements
    const bf16_t* gA[2];
    const bf16_t* gB[2];
#pragma unroll
    for (int j = 0; j < 2; j++) {
        gA[j] = Abf + (size_t)(bm0 + j * 64 + srow) * D_DIM + scol;
        gB[j] = Wt + (size_t)(bn0 + j * 64 + srow) * D_DIM + scol;
    }

    // frag reads (verified 0-conflict): row = frow in 16-row group
    const int frow = lane & 15;
    const int q = lane >> 4;
    const int fx7 = frow & 7;
    const int lof0 = frow * 64 + (((q) ^ fx7) << 3);          // ks=0, elems
    const int lof1 = frow * 64 + (((4 + q) ^ fx7) << 3);      // ks=1, elems

    // prologue: tile 0 into buf0
    STAGE(lds_a0, lds_b0, 0);
    VMCNT0();
    BAR();

    // main loop: 15 iters x 2 K-tiles (computes tiles 0..29), static ping-pong
#pragma unroll 1
    for (int i = 0; i < 15; ++i) {
        const int tt = 2 * i;
        STAGE(lds_a1, lds_b1, tt + 1);
        COMPUTE(lds_a0, lds_b0);
        VMCNT0();
        BAR();
        STAGE(lds_a0, lds_b0, tt + 2);
        COMPUTE(lds_a1, lds_b1);
        VMCNT0();
        BAR();
    }
    // tail: tile 30 in buf0; stage 31 -> buf1; compute 30; compute 31
    STAGE(lds_a1, lds_b1, 31);
    COMPUTE(lds_a0, lds_b0);
    VMCNT0();
    BAR();
    COMPUTE(lds_a1, lds_b1);

    // epilogue: C/D layout col = lane&15, row = (lane>>4)*4 + reg  [m89-verified]
    const int seg = bn0 >> 11;                        // 0=A, 1=dt, 2=rawB
    const int dbase = (bn0 & 2047) + wc + (lane & 15);
    const int rowbase = bm0 + wr + (q << 2);

    if (seg == 0) {
        float bias[2];
#pragma unroll
        for (int n = 0; n < 2; n++) bias[n] = bA[dbase + n * 16];
#pragma unroll
        for (int m = 0; m < 4; m++)
#pragma unroll
            for (int n = 0; n < 2; n++)
#pragma unroll
                for (int r = 0; r < 4; r++) {
                    size_t idx = (size_t)(rowbase + m * 16 + r) * D_DIM + dbase + n * 16;
                    outA[idx] = 1.0f / (1.0f + __expf(-(acc[m][n][r] + bias[n])));
                }
    } else if (seg == 1) {
        float bias[2], sc[2];
#pragma unroll
        for (int n = 0; n < 2; n++) { bias[n] = bdt[dbase + n * 16]; sc[n] = scales[dbase + n * 16]; }
#pragma unroll
        for (int m = 0; m < 4; m++)
#pragma unroll
            for (int n = 0; n < 2; n++)
#pragma unroll
                for (int r = 0; r < 4; r++) {
                    size_t idx = (size_t)(rowbase + m * 16 + r) * D_DIM + dbase + n * 16;
                    float xx = acc[m][n][r] + bias[n];
                    float sp = xx > 0.f ? xx + log1pf(__expf(-xx)) : log1pf(__expf(xx));
                    outDT[idx] = sp * 0.1f * sc[n];
                }
    } else {
        float bias[2];
#pragma unroll
        for (int n = 0; n < 2; n++) bias[n] = bB[dbase + n * 16];
#pragma unroll
        for (int m = 0; m < 4; m++)
#pragma unroll
            for (int n = 0; n < 2; n++)
#pragma unroll
                for (int r = 0; r < 4; r++) {
                    size_t idx = (size_t)(rowbase + m * 16 + r) * D_DIM + dbase + n * 16;
                    outB[idx] = acc[m][n][r] + bias[n];
                }
    }
}

// ---------------- scan pass 1: per-chunk affine aggregates ----------------
// step map: v' = a v + bv ; x' = x + dt v'  =>  (P,R,U,W):
//   v_out = P v + U ; x_out = R v + x + W
// 4 adjacent d-channels per thread (f32x4 = 16B/lane loads, G13).
__global__ __launch_bounds__(256) void scan_pass1_kernel(
    const float* __restrict__ Aarr, const float* __restrict__ Braw,
    const float* __restrict__ dtv, float4* __restrict__ agg)
{
    int pp = blockIdx.x * 256 + threadIdx.x;    // 32768 quad-threads
    int dq = (pp & 511) << 2;                   // d base, 4 channels
    int c = (pp >> 9) & (NCH - 1);
    int b = pp >> 13;
    size_t base = ((size_t)(b * L_SEQ + c * CHUNK)) * D_DIM + dq;
    float P[4], R[4], U[4], W[4];
#pragma unroll
    for (int j = 0; j < 4; j++) { P[j] = 1.f; R[j] = 0.f; U[j] = 0.f; W[j] = 0.f; }
#pragma unroll 2
    for (int tt = 0; tt < CHUNK; tt++) {
        size_t idx = base + (size_t)tt * D_DIM;
        f32x4 a4  = *(const f32x4*)&Aarr[idx];
        f32x4 rb4 = *(const f32x4*)&Braw[idx];
        f32x4 dt4 = *(const f32x4*)&dtv[idx];
#pragma unroll
        for (int j = 0; j < 4; j++) {
            float bv = rb4[j] * dt4[j];
            float da = dt4[j] * a4[j];
            R[j] = da * P[j] + R[j];
            W[j] = da * U[j] + dt4[j] * bv + W[j];
            U[j] = a4[j] * U[j] + bv;
            P[j] = a4[j] * P[j];
        }
    }
    int ch = ((b * NCH + c) << 11) + dq;
#pragma unroll
    for (int j = 0; j < 4; j++)
        agg[ch + j] = make_float4(P[j], R[j], U[j], W[j]);
}

// ---------------- scan pass 2: combine chunk aggregates ----------------
__global__ __launch_bounds__(256) void scan_pass2_kernel(
    const float4* __restrict__ agg, float2* __restrict__ pre)
{
    int tid = blockIdx.x * 256 + threadIdx.x;   // 8192 channels
    int d = tid & (D_DIM - 1);
    int b = tid >> 11;
    float v = 0.f, x = 0.f;
#pragma unroll
    for (int c = 0; c < NCH; c++) {
        int i = ((b * NCH + c) << 11) + d;
        float4 g = agg[i];
        pre[i] = make_float2(v, x);             // state entering chunk c
        float vn = g.x * v + g.z;
        x = g.y * v + x + g.w;                  // uses old v
        v = vn;
    }
}

// ---------------- scan pass 3: replay chunk, write outputs in place ----------------
// A staged in xout, rawB staged in vout; overwritten in place
// (read-before-write, same element, same thread). 4 channels/thread, f32x4.
__global__ __launch_bounds__(256) void scan_pass3_kernel(
    const float* __restrict__ dtv, const float2* __restrict__ pre,
    float* __restrict__ xout, float* __restrict__ vout)
{
    int pp = blockIdx.x * 256 + threadIdx.x;    // 32768 quad-threads
    int dq = (pp & 511) << 2;
    int c = (pp >> 9) & (NCH - 1);
    int b = pp >> 13;
    int ch = ((b * NCH + c) << 11) + dq;
    f32x4 p01 = *(const f32x4*)&pre[ch];        // {v0,x0,v1,x1}
    f32x4 p23 = *(const f32x4*)&pre[ch + 2];    // {v2,x2,v3,x3}
    float v[4], x[4];
    v[0] = p01[0]; x[0] = p01[1]; v[1] = p01[2]; x[1] = p01[3];
    v[2] = p23[0]; x[2] = p23[1]; v[3] = p23[2]; x[3] = p23[3];
    size_t base = ((size_t)(b * L_SEQ + c * CHUNK)) * D_DIM + dq;
#pragma unroll 2
    for (int tt = 0; tt < CHUNK; tt++) {
        size_t idx = base + (size_t)tt * D_DIM;
        f32x4 a4  = *(const f32x4*)&xout[idx];   // A (staged)
        f32x4 rb4 = *(const f32x4*)&vout[idx];   // rawB (staged)
        f32x4 dt4 = *(const f32x4*)&dtv[idx];
        f32x4 vo, xo;
#pragma unroll
        for (int j = 0; j < 4; j++) {
            v[j] = a4[j] * v[j] + rb4[j] * dt4[j];
            x[j] = x[j] + v[j] * dt4[j];
            vo[j] = v[j];
            xo[j] = x[j];
        }
        *(f32x4*)&vout[idx] = vo;
        *(f32x4*)&xout[idx] = xo;
    }
}

extern "C" void kernel_launch(void* const* d_in, const int* in_sizes, int n_in,
                              void* d_out, int out_size, void* d_ws, size_t ws_size,
                              hipStream_t stream) {
    // inputs: 0:x 1:v 2:force 3:WA 4:bA 5:WB 6:bB 7:Wdt 8:bdt 9:scales
    const float* force  = (const float*)d_in[2];
    const float* WA     = (const float*)d_in[3];
    const float* bA     = (const float*)d_in[4];
    const float* WB     = (const float*)d_in[5];
    const float* bB     = (const float*)d_in[6];
    const float* Wdt    = (const float*)d_in[7];
    const float* bdt    = (const float*)d_in[8];
    const float* scales = (const float*)d_in[9];

    float* xout = (float*)d_out;                          // x_seq [8192*2048]
    float* vout = xout + (size_t)M_ROWS * D_DIM;          // v_seq

    // ws layout (123 MiB): R1 layout
    char* ws = (char*)d_ws;
    bf16_t* fbf = (bf16_t*)ws;                                     // 32 MB
    bf16_t* wt  = (bf16_t*)(ws + (size_t)33554432);                // 24 MB
    float*  dtv = (float*)(ws + (size_t)33554432 + 25165824);      // 64 MB
    float4* agg = (float4*)(ws + (size_t)33554432 + 25165824 + 67108864); // 2 MB
    float2* pre = (float2*)(ws + (size_t)33554432 + 25165824 + 67108864 + 2097152); // 1 MB

    // 1) force -> bf16
    {
        int n8 = M_ROWS * D_DIM / 8;
        cvt_bf16_kernel<<<n8 / 256, 256, 0, stream>>>(force, fbf, n8);
    }
    // 2) transpose + convert weights into concat [6144][2048]: A | dt | B
    {
        dim3 grid(D_DIM / 32, D_DIM / 32, 3), block(32, 8);
        transpose_w_kernel<<<grid, block, 0, stream>>>(WA, Wdt, WB, wt);
    }
    // 3) fused GEMM + activations (BK=64, 2-phase dbuf, 8 waves / 128^2)
    {
        dim3 grid(M_ROWS / 128, NT_COLS / 128);   // (64, 48)
        gemm_fused_kernel<<<grid, 512, 0, stream>>>(fbf, wt, bA, bdt, bB, scales,
                                                    xout, dtv, vout);
    }
    // 4-6) chunked associative scan (4 channels per thread, 16B/lane)
    scan_pass1_kernel<<<(B_SZ * NCH * D_DIM / 4) / 256, 256, 0, stream>>>(xout, vout, dtv, agg);
    scan_pass2_kernel<<<(B_SZ * D_DIM) / 256, 256, 0, stream>>>(agg, pre);
    scan_pass3_kernel<<<(B_SZ * NCH * D_DIM / 4) / 256, 256, 0, stream>>>(dtv, pre, xout, vout);
}

// Round 18
// 412.853 us; speedup vs baseline: 1.0171x; 1.0130x over previous
//
#include <hip/hip_runtime.h>
#include <hip/hip_bf16.h>
#include <cstdint>
#include <cstddef>

#define D_DIM 2048
#define L_SEQ 2048
#define B_SZ 4
#define M_ROWS (B_SZ * L_SEQ)   /* 8192 */
#define NT_COLS (3 * D_DIM)     /* 6144: seg0=A, seg1=dt, seg2=rawB */
#define NCH 32
#define CHUNK (L_SEQ / NCH)     /* 64 */

typedef __bf16 bf16_t;
typedef bf16_t bf16x8 __attribute__((ext_vector_type(8)));
typedef float f32x4 __attribute__((ext_vector_type(4)));

__device__ __forceinline__ void gl_lds16(const void* g, void* l) {
    __builtin_amdgcn_global_load_lds(
        (const __attribute__((address_space(1))) unsigned int*)g,
        (__attribute__((address_space(3))) unsigned int*)l, 16, 0, 0);
}

#define BAR()    asm volatile("s_barrier" ::: "memory")
#define VMCNT0() asm volatile("s_waitcnt vmcnt(0)" ::: "memory")

// ---------------- convert force f32 -> bf16 (16B stores) ----------------
__global__ __launch_bounds__(256) void cvt_bf16_kernel(
    const float* __restrict__ in, bf16_t* __restrict__ out, int n8)
{
    int i = blockIdx.x * 256 + threadIdx.x;
    if (i >= n8) return;
    float4 f0 = ((const float4*)in)[2 * i];
    float4 f1 = ((const float4*)in)[2 * i + 1];
    bf16x8 o;
    o[0] = (bf16_t)f0.x; o[1] = (bf16_t)f0.y; o[2] = (bf16_t)f0.z; o[3] = (bf16_t)f0.w;
    o[4] = (bf16_t)f1.x; o[5] = (bf16_t)f1.y; o[6] = (bf16_t)f1.z; o[7] = (bf16_t)f1.w;
    ((bf16x8*)out)[i] = o;
}

// ------- transpose W[k][j] -> Wt[j][k] with f32->bf16; z picks matrix -------
__global__ __launch_bounds__(256) void transpose_w_kernel(
    const float* __restrict__ W0, const float* __restrict__ W1,
    const float* __restrict__ W2, bf16_t* __restrict__ Wt)
{
    __shared__ float tile[32][33];
    const float* W = (blockIdx.z == 0) ? W0 : (blockIdx.z == 1) ? W1 : W2;
    bf16_t* dst = Wt + (size_t)blockIdx.z * D_DIM * D_DIM;
    int j0 = blockIdx.x * 32, k0 = blockIdx.y * 32;
    int tx = threadIdx.x, ty = threadIdx.y;      // block (32, 8)
#pragma unroll
    for (int i = 0; i < 4; i++) {
        int k = k0 + ty + i * 8;
        tile[ty + i * 8][tx] = W[(size_t)k * D_DIM + j0 + tx];
    }
    __syncthreads();
#pragma unroll
    for (int i = 0; i < 4; i++) {
        int j = j0 + ty + i * 8;
        dst[(size_t)j * D_DIM + k0 + tx] = (bf16_t)tile[tx][ty + i * 8];
    }
}

// ---------------- fused bf16 GEMM: [8192 x 2048] @ [2048 x 6144] ----------------
// R12/R15 configuration — best-TOTAL config (gemm ~319-327us, total 407.5us,
// reproduced three times). 128^2 tile, BK=64, 8 waves (2m x 4n), 2-phase
// double-buffer, one vmcnt(0)+barrier per K-tile. 16x16x32 MFMA.
// Verified 0-conflict swizzle pair (R7/R8/R12):
//   stage: LDS dest linear, global col slot ^= (row&7)
//   read : slot = (ks*4 + (lane>>4)) ^ (frow&7)
// Ledger (do not revisit): structure changes 0-for-6 (R2/R3/R9/R10/R11/R14).
// R16: 256^2 tile = faster GEMM but slower TOTAL (L3 coupling with scan).
// R17: f32x4 scan = fewer threads -> latency-bound regression (TLP > width).
// R5: bf16 epilogue stores -> acc spill (keep f32). R9: 32x32 MFMA frag
// reads conflict 2.5e7 (keep 16x16). 2-phase wall (m233) binds at ~650 TF.
#define STAGE(LA, LB, T) {                                                     \
    const size_t kofs_ = (size_t)(T) * 64;                                     \
    _Pragma("unroll") for (int j = 0; j < 2; j++) {                            \
        gl_lds16(gA[j] + kofs_, (LA) + j * 4096 + w * 512);                    \
        gl_lds16(gB[j] + kofs_, (LB) + j * 4096 + w * 512);                    \
    } }

#define COMPUTE(LA, LB) {                                                      \
    bf16x8 af[4], bfr[2];                                                      \
    _Pragma("unroll") for (int m = 0; m < 4; m++)                              \
        af[m] = *(const bf16x8*)&(LA)[(wr + m * 16) * 64 + lof0];              \
    _Pragma("unroll") for (int n = 0; n < 2; n++)                              \
        bfr[n] = *(const bf16x8*)&(LB)[(wc + n * 16) * 64 + lof0];             \
    __builtin_amdgcn_s_setprio(1);                                             \
    _Pragma("unroll") for (int m = 0; m < 4; m++)                              \
        _Pragma("unroll") for (int n = 0; n < 2; n++)                          \
            acc[m][n] = __builtin_amdgcn_mfma_f32_16x16x32_bf16(               \
                af[m], bfr[n], acc[m][n], 0, 0, 0);                            \
    __builtin_amdgcn_s_setprio(0);                                             \
    _Pragma("unroll") for (int m = 0; m < 4; m++)                              \
        af[m] = *(const bf16x8*)&(LA)[(wr + m * 16) * 64 + lof1];              \
    _Pragma("unroll") for (int n = 0; n < 2; n++)                              \
        bfr[n] = *(const bf16x8*)&(LB)[(wc + n * 16) * 64 + lof1];             \
    __builtin_amdgcn_s_setprio(1);                                             \
    _Pragma("unroll") for (int m = 0; m < 4; m++)                              \
        _Pragma("unroll") for (int n = 0; n < 2; n++)                          \
            acc[m][n] = __builtin_amdgcn_mfma_f32_16x16x32_bf16(               \
                af[m], bfr[n], acc[m][n], 0, 0, 0);                            \
    __builtin_amdgcn_s_setprio(0);                                             \
}

__global__ __launch_bounds__(512) void gemm_fused_kernel(
    const bf16_t* __restrict__ Abf,   // force bf16 [8192][2048]
    const bf16_t* __restrict__ Wt,    // [6144][2048] (W^T, concat A|dt|B)
    const float* __restrict__ bA, const float* __restrict__ bdt,
    const float* __restrict__ bB, const float* __restrict__ scales,
    float* __restrict__ outA,         // -> d_out x-region (staging)
    float* __restrict__ outDT,        // -> ws
    float* __restrict__ outB)         // -> d_out v-region (staging)
{
    __shared__ bf16_t lds_a0[128 * 64];   // 16 KB
    __shared__ bf16_t lds_a1[128 * 64];
    __shared__ bf16_t lds_b0[128 * 64];
    __shared__ bf16_t lds_b1[128 * 64];   // total 64 KB

    const int bm0 = blockIdx.x * 128;         // M block (fastest)
    const int bn0 = blockIdx.y * 128;         // NT block
    const int t = threadIdx.x;                // 0..511
    const int lane = t & 63, w = t >> 6;      // 8 waves
    const int wr = (w >> 2) * 64;             // 2 m-groups
    const int wc = (w & 3) * 32;              // 4 n-groups

    f32x4 acc[4][2] = {};

    // staging: issue j covers rows j*64 + (t>>3); linear 16B slot t&7,
    // global col pre-swizzled slot ^ (row&7) = (t&7) ^ ((t>>3)&7).
    const int srow = t >> 3;                  // 0..63
    const int scol = (((t & 7) ^ ((t >> 3) & 7)) << 3);   // elements
    const bf16_t* gA[2];
    const bf16_t* gB[2];
#pragma unroll
    for (int j = 0; j < 2; j++) {
        gA[j] = Abf + (size_t)(bm0 + j * 64 + srow) * D_DIM + scol;
        gB[j] = Wt + (size_t)(bn0 + j * 64 + srow) * D_DIM + scol;
    }

    // frag reads (verified 0-conflict): row = frow in 16-row group
    const int frow = lane & 15;
    const int q = lane >> 4;
    const int fx7 = frow & 7;
    const int lof0 = frow * 64 + (((q) ^ fx7) << 3);          // ks=0, elems
    const int lof1 = frow * 64 + (((4 + q) ^ fx7) << 3);      // ks=1, elems

    // prologue: tile 0 into buf0
    STAGE(lds_a0, lds_b0, 0);
    VMCNT0();
    BAR();

    // main loop: 15 iters x 2 K-tiles (computes tiles 0..29), static ping-pong
#pragma unroll 1
    for (int i = 0; i < 15; ++i) {
        const int tt = 2 * i;
        STAGE(lds_a1, lds_b1, tt + 1);
        COMPUTE(lds_a0, lds_b0);
        VMCNT0();
        BAR();
        STAGE(lds_a0, lds_b0, tt + 2);
        COMPUTE(lds_a1, lds_b1);
        VMCNT0();
        BAR();
    }
    // tail: tile 30 in buf0; stage 31 -> buf1; compute 30; compute 31
    STAGE(lds_a1, lds_b1, 31);
    COMPUTE(lds_a0, lds_b0);
    VMCNT0();
    BAR();
    COMPUTE(lds_a1, lds_b1);

    // epilogue: C/D layout col = lane&15, row = (lane>>4)*4 + reg  [m89-verified]
    const int seg = bn0 >> 11;                        // 0=A, 1=dt, 2=rawB
    const int dbase = (bn0 & 2047) + wc + (lane & 15);
    const int rowbase = bm0 + wr + (q << 2);

    if (seg == 0) {
        float bias[2];
#pragma unroll
        for (int n = 0; n < 2; n++) bias[n] = bA[dbase + n * 16];
#pragma unroll
        for (int m = 0; m < 4; m++)
#pragma unroll
            for (int n = 0; n < 2; n++)
#pragma unroll
                for (int r = 0; r < 4; r++) {
                    size_t idx = (size_t)(rowbase + m * 16 + r) * D_DIM + dbase + n * 16;
                    outA[idx] = 1.0f / (1.0f + __expf(-(acc[m][n][r] + bias[n])));
                }
    } else if (seg == 1) {
        float bias[2], sc[2];
#pragma unroll
        for (int n = 0; n < 2; n++) { bias[n] = bdt[dbase + n * 16]; sc[n] = scales[dbase + n * 16]; }
#pragma unroll
        for (int m = 0; m < 4; m++)
#pragma unroll
            for (int n = 0; n < 2; n++)
#pragma unroll
                for (int r = 0; r < 4; r++) {
                    size_t idx = (size_t)(rowbase + m * 16 + r) * D_DIM + dbase + n * 16;
                    float xx = acc[m][n][r] + bias[n];
                    float sp = xx > 0.f ? xx + log1pf(__expf(-xx)) : log1pf(__expf(xx));
                    outDT[idx] = sp * 0.1f * sc[n];
                }
    } else {
        float bias[2];
#pragma unroll
        for (int n = 0; n < 2; n++) bias[n] = bB[dbase + n * 16];
#pragma unroll
        for (int m = 0; m < 4; m++)
#pragma unroll
            for (int n = 0; n < 2; n++)
#pragma unroll
                for (int r = 0; r < 4; r++) {
                    size_t idx = (size_t)(rowbase + m * 16 + r) * D_DIM + dbase + n * 16;
                    outB[idx] = acc[m][n][r] + bias[n];
                }
    }
}

// ---------------- scan pass 1: per-chunk affine aggregates ----------------
// step map: v' = a v + bv ; x' = x + dt v'  =>  (P,R,U,W):
//   v_out = P v + U ; x_out = R v + x + W
// 2 adjacent d-channels per thread (float2 loads); NCH=32 for 2 blocks/CU
// (R17 lesson: scan passes are latency-bound; TLP > load width).
__global__ __launch_bounds__(256) void scan_pass1_kernel(
    const float* __restrict__ Aarr, const float* __restrict__ Braw,
    const float* __restrict__ dtv, float4* __restrict__ agg)
{
    int pp = blockIdx.x * 256 + threadIdx.x;    // 131072 pair-threads
    int dp = (pp & 1023) << 1;                  // d pair base
    int c = (pp >> 10) & (NCH - 1);
    int b = pp >> 15;
    size_t base = ((size_t)(b * L_SEQ + c * CHUNK)) * D_DIM + dp;
    float P0 = 1.f, R0 = 0.f, U0 = 0.f, W0 = 0.f;
    float P1 = 1.f, R1 = 0.f, U1 = 0.f, W1 = 0.f;
#pragma unroll 4
    for (int tt = 0; tt < CHUNK; tt++) {
        size_t idx = base + (size_t)tt * D_DIM;
        float2 a2  = *(const float2*)&Aarr[idx];
        float2 rb2 = *(const float2*)&Braw[idx];
        float2 dt2 = *(const float2*)&dtv[idx];
        float bv0 = rb2.x * dt2.x, bv1 = rb2.y * dt2.y;
        float da0 = dt2.x * a2.x,  da1 = dt2.y * a2.y;
        R0 = da0 * P0 + R0;  W0 = da0 * U0 + dt2.x * bv0 + W0;
        U0 = a2.x * U0 + bv0;  P0 = a2.x * P0;
        R1 = da1 * P1 + R1;  W1 = da1 * U1 + dt2.y * bv1 + W1;
        U1 = a2.y * U1 + bv1;  P1 = a2.y * P1;
    }
    int ch = ((b * NCH + c) << 11) + dp;
    agg[ch]     = make_float4(P0, R0, U0, W0);
    agg[ch + 1] = make_float4(P1, R1, U1, W1);
}

// ---------------- scan pass 2: combine chunk aggregates ----------------
__global__ __launch_bounds__(256) void scan_pass2_kernel(
    const float4* __restrict__ agg, float2* __restrict__ pre)
{
    int tid = blockIdx.x * 256 + threadIdx.x;   // 8192 channels
    int d = tid & (D_DIM - 1);
    int b = tid >> 11;
    float v = 0.f, x = 0.f;
#pragma unroll
    for (int c = 0; c < NCH; c++) {
        int i = ((b * NCH + c) << 11) + d;
        float4 g = agg[i];
        pre[i] = make_float2(v, x);             // state entering chunk c
        float vn = g.x * v + g.z;
        x = g.y * v + x + g.w;                  // uses old v
        v = vn;
    }
}

// ---------------- scan pass 3: replay chunk, write outputs in place ----------------
// A staged in xout, rawB staged in vout; overwritten in place
// (read-before-write, same element, same thread).
__global__ __launch_bounds__(256) void scan_pass3_kernel(
    const float* __restrict__ dtv, const float2* __restrict__ pre,
    float* __restrict__ xout, float* __restrict__ vout)
{
    int pp = blockIdx.x * 256 + threadIdx.x;    // 131072 pair-threads
    int dp = (pp & 1023) << 1;
    int c = (pp >> 10) & (NCH - 1);
    int b = pp >> 15;
    int ch = ((b * NCH + c) << 11) + dp;
    float4 pv = *(const float4*)&pre[ch];       // {v0,x0,v1,x1}
    float v0 = pv.x, x0 = pv.y, v1 = pv.z, x1 = pv.w;
    size_t base = ((size_t)(b * L_SEQ + c * CHUNK)) * D_DIM + dp;
#pragma unroll 4
    for (int tt = 0; tt < CHUNK; tt++) {
        size_t idx = base + (size_t)tt * D_DIM;
        float2 a2  = *(const float2*)&xout[idx];   // A (staged)
        float2 rb2 = *(const float2*)&vout[idx];   // rawB (staged)
        float2 dt2 = *(const float2*)&dtv[idx];
        v0 = a2.x * v0 + rb2.x * dt2.x;
        x0 = x0 + v0 * dt2.x;
        v1 = a2.y * v1 + rb2.y * dt2.y;
        x1 = x1 + v1 * dt2.y;
        *(float2*)&vout[idx] = make_float2(v0, v1);
        *(float2*)&xout[idx] = make_float2(x0, x1);
    }
}

extern "C" void kernel_launch(void* const* d_in, const int* in_sizes, int n_in,
                              void* d_out, int out_size, void* d_ws, size_t ws_size,
                              hipStream_t stream) {
    // inputs: 0:x 1:v 2:force 3:WA 4:bA 5:WB 6:bB 7:Wdt 8:bdt 9:scales
    const float* force  = (const float*)d_in[2];
    const float* WA     = (const float*)d_in[3];
    const float* bA     = (const float*)d_in[4];
    const float* WB     = (const float*)d_in[5];
    const float* bB     = (const float*)d_in[6];
    const float* Wdt    = (const float*)d_in[7];
    const float* bdt    = (const float*)d_in[8];
    const float* scales = (const float*)d_in[9];

    float* xout = (float*)d_out;                          // x_seq [8192*2048]
    float* vout = xout + (size_t)M_ROWS * D_DIM;          // v_seq

    // ws layout (123 MiB total, unchanged): fbf 32MB | wt 24MB | dtv 64MB.
    // agg (4MB) + pre (2MB) ALIAS the fbf region — fbf is dead after the
    // GEMM reads it, and cvt rewrites it fresh at the start of every replay.
    char* ws = (char*)d_ws;
    bf16_t* fbf = (bf16_t*)ws;                                     // 32 MB
    bf16_t* wt  = (bf16_t*)(ws + (size_t)33554432);                // 24 MB
    float*  dtv = (float*)(ws + (size_t)33554432 + 25165824);      // 64 MB
    float4* agg = (float4*)ws;                                     // 4 MB (alias fbf)
    float2* pre = (float2*)(ws + (size_t)4194304);                 // 2 MB (alias fbf)

    // 1) force -> bf16
    {
        int n8 = M_ROWS * D_DIM / 8;
        cvt_bf16_kernel<<<n8 / 256, 256, 0, stream>>>(force, fbf, n8);
    }
    // 2) transpose + convert weights into concat [6144][2048]: A | dt | B
    {
        dim3 grid(D_DIM / 32, D_DIM / 32, 3), block(32, 8);
        transpose_w_kernel<<<grid, block, 0, stream>>>(WA, Wdt, WB, wt);
    }
    // 3) fused GEMM + activations (BK=64, 2-phase dbuf, 8 waves / 128^2)
    {
        dim3 grid(M_ROWS / 128, NT_COLS / 128);   // (64, 48)
        gemm_fused_kernel<<<grid, 512, 0, stream>>>(fbf, wt, bA, bdt, bB, scales,
                                                    xout, dtv, vout);
    }
    // 4-6) chunked associative scan (NCH=32, 2 channels per thread)
    scan_pass1_kernel<<<(B_SZ * NCH * D_DIM / 2) / 256, 256, 0, stream>>>(xout, vout, dtv, agg);
    scan_pass2_kernel<<<(B_SZ * D_DIM) / 256, 256, 0, stream>>>(agg, pre);
    scan_pass3_kernel<<<(B_SZ * NCH * D_DIM / 2) / 256, 256, 0, stream>>>(dtv, pre, xout, vout);
}

// Round 19
// 407.343 us; speedup vs baseline: 1.0309x; 1.0135x over previous
//
#include <hip/hip_runtime.h>
#include <hip/hip_bf16.h>
#include <cstdint>
#include <cstddef>

#define D_DIM 2048
#define L_SEQ 2048
#define B_SZ 4
#define M_ROWS (B_SZ * L_SEQ)   /* 8192 */
#define NT_COLS (3 * D_DIM)     /* 6144: seg0=A, seg1=dt, seg2=rawB */
#define NCH 16
#define CHUNK (L_SEQ / NCH)     /* 128 */

typedef __bf16 bf16_t;
typedef bf16_t bf16x8 __attribute__((ext_vector_type(8)));
typedef float f32x4 __attribute__((ext_vector_type(4)));

__device__ __forceinline__ void gl_lds16(const void* g, void* l) {
    __builtin_amdgcn_global_load_lds(
        (const __attribute__((address_space(1))) unsigned int*)g,
        (__attribute__((address_space(3))) unsigned int*)l, 16, 0, 0);
}

#define BAR()    asm volatile("s_barrier" ::: "memory")
#define VMCNT0() asm volatile("s_waitcnt vmcnt(0)" ::: "memory")

// ---------------- convert force f32 -> bf16 (16B stores) ----------------
__global__ __launch_bounds__(256) void cvt_bf16_kernel(
    const float* __restrict__ in, bf16_t* __restrict__ out, int n8)
{
    int i = blockIdx.x * 256 + threadIdx.x;
    if (i >= n8) return;
    float4 f0 = ((const float4*)in)[2 * i];
    float4 f1 = ((const float4*)in)[2 * i + 1];
    bf16x8 o;
    o[0] = (bf16_t)f0.x; o[1] = (bf16_t)f0.y; o[2] = (bf16_t)f0.z; o[3] = (bf16_t)f0.w;
    o[4] = (bf16_t)f1.x; o[5] = (bf16_t)f1.y; o[6] = (bf16_t)f1.z; o[7] = (bf16_t)f1.w;
    ((bf16x8*)out)[i] = o;
}

// ------- transpose W[k][j] -> Wt[j][k] with f32->bf16; z picks matrix -------
__global__ __launch_bounds__(256) void transpose_w_kernel(
    const float* __restrict__ W0, const float* __restrict__ W1,
    const float* __restrict__ W2, bf16_t* __restrict__ Wt)
{
    __shared__ float tile[32][33];
    const float* W = (blockIdx.z == 0) ? W0 : (blockIdx.z == 1) ? W1 : W2;
    bf16_t* dst = Wt + (size_t)blockIdx.z * D_DIM * D_DIM;
    int j0 = blockIdx.x * 32, k0 = blockIdx.y * 32;
    int tx = threadIdx.x, ty = threadIdx.y;      // block (32, 8)
#pragma unroll
    for (int i = 0; i < 4; i++) {
        int k = k0 + ty + i * 8;
        tile[ty + i * 8][tx] = W[(size_t)k * D_DIM + j0 + tx];
    }
    __syncthreads();
#pragma unroll
    for (int i = 0; i < 4; i++) {
        int j = j0 + ty + i * 8;
        dst[(size_t)j * D_DIM + k0 + tx] = (bf16_t)tile[tx][ty + i * 8];
    }
}

// ---------------- fused bf16 GEMM: [8192 x 2048] @ [2048 x 6144] ----------------
// FINAL — R12/R15 configuration, best measured TOTAL (407.5us, reproduced
// 3x). 128^2 tile, BK=64, 8 waves (2m x 4n), 2-phase double-buffer, one
// vmcnt(0)+barrier per K-tile, 16x16x32 MFMA, f32 epilogue.
// Verified 0-conflict swizzle pair (R7/R8/R12):
//   stage: LDS dest linear, global col slot ^= (row&7)
//   read : slot = (ks*4 + (lane>>4)) ^ (frow&7)
// Session ledger (all measured, do not revisit):
//  - Structure changes 0-for-6: R2 ks-split 8ph, R3 4-ring, R9/R10 counted-
//    vmcnt rings, R11 A-in-reg (805us), R14 256^2 8-phase (VGPR spill, 3.6ms).
//  - Parameter wins 4-for-4: BK64 (+10%), 2-phase dbuf (+15%), 8-wave (+4%),
//    swizzle (enables BK64).
//  - R5: bf16 epilogue stores -> acc spill-to-scratch (VGPR 80->32, 21GB).
//  - R9: 32x32 MFMA frag reads = 2.5e7 conflicts; 16x16 pattern = 0.
//  - R16: 256^2 tile = faster GEMM (305us) but slower TOTAL (420us): bigger
//    output flush evicts scan inputs from L3 (GEMM and scan cache-coupled).
//  - R17: f32x4 scan = latency-bound regression (TLP > width).
//  - R18: NCH=32 scan = +5us (pass2 serial combine doubles).
//  - 2-phase stage+drain wall (m233) binds the GEMM at ~650 TF.
#define STAGE(LA, LB, T) {                                                     \
    const size_t kofs_ = (size_t)(T) * 64;                                     \
    _Pragma("unroll") for (int j = 0; j < 2; j++) {                            \
        gl_lds16(gA[j] + kofs_, (LA) + j * 4096 + w * 512);                    \
        gl_lds16(gB[j] + kofs_, (LB) + j * 4096 + w * 512);                    \
    } }

#define COMPUTE(LA, LB) {                                                      \
    bf16x8 af[4], bfr[2];                                                      \
    _Pragma("unroll") for (int m = 0; m < 4; m++)                              \
        af[m] = *(const bf16x8*)&(LA)[(wr + m * 16) * 64 + lof0];              \
    _Pragma("unroll") for (int n = 0; n < 2; n++)                              \
        bfr[n] = *(const bf16x8*)&(LB)[(wc + n * 16) * 64 + lof0];             \
    __builtin_amdgcn_s_setprio(1);                                             \
    _Pragma("unroll") for (int m = 0; m < 4; m++)                              \
        _Pragma("unroll") for (int n = 0; n < 2; n++)                          \
            acc[m][n] = __builtin_amdgcn_mfma_f32_16x16x32_bf16(               \
                af[m], bfr[n], acc[m][n], 0, 0, 0);                            \
    __builtin_amdgcn_s_setprio(0);                                             \
    _Pragma("unroll") for (int m = 0; m < 4; m++)                              \
        af[m] = *(const bf16x8*)&(LA)[(wr + m * 16) * 64 + lof1];              \
    _Pragma("unroll") for (int n = 0; n < 2; n++)                              \
        bfr[n] = *(const bf16x8*)&(LB)[(wc + n * 16) * 64 + lof1];             \
    __builtin_amdgcn_s_setprio(1);                                             \
    _Pragma("unroll") for (int m = 0; m < 4; m++)                              \
        _Pragma("unroll") for (int n = 0; n < 2; n++)                          \
            acc[m][n] = __builtin_amdgcn_mfma_f32_16x16x32_bf16(               \
                af[m], bfr[n], acc[m][n], 0, 0, 0);                            \
    __builtin_amdgcn_s_setprio(0);                                             \
}

__global__ __launch_bounds__(512) void gemm_fused_kernel(
    const bf16_t* __restrict__ Abf,   // force bf16 [8192][2048]
    const bf16_t* __restrict__ Wt,    // [6144][2048] (W^T, concat A|dt|B)
    const float* __restrict__ bA, const float* __restrict__ bdt,
    const float* __restrict__ bB, const float* __restrict__ scales,
    float* __restrict__ outA,         // -> d_out x-region (staging)
    float* __restrict__ outDT,        // -> ws
    float* __restrict__ outB)         // -> d_out v-region (staging)
{
    __shared__ bf16_t lds_a0[128 * 64];   // 16 KB
    __shared__ bf16_t lds_a1[128 * 64];
    __shared__ bf16_t lds_b0[128 * 64];
    __shared__ bf16_t lds_b1[128 * 64];   // total 64 KB

    const int bm0 = blockIdx.x * 128;         // M block (fastest)
    const int bn0 = blockIdx.y * 128;         // NT block
    const int t = threadIdx.x;                // 0..511
    const int lane = t & 63, w = t >> 6;      // 8 waves
    const int wr = (w >> 2) * 64;             // 2 m-groups
    const int wc = (w & 3) * 32;              // 4 n-groups

    f32x4 acc[4][2] = {};

    // staging: issue j covers rows j*64 + (t>>3); linear 16B slot t&7,
    // global col pre-swizzled slot ^ (row&7) = (t&7) ^ ((t>>3)&7).
    const int srow = t >> 3;                  // 0..63
    const int scol = (((t & 7) ^ ((t >> 3) & 7)) << 3);   // elements
    const bf16_t* gA[2];
    const bf16_t* gB[2];
#pragma unroll
    for (int j = 0; j < 2; j++) {
        gA[j] = Abf + (size_t)(bm0 + j * 64 + srow) * D_DIM + scol;
        gB[j] = Wt + (size_t)(bn0 + j * 64 + srow) * D_DIM + scol;
    }

    // frag reads (verified 0-conflict): row = frow in 16-row group
    const int frow = lane & 15;
    const int q = lane >> 4;
    const int fx7 = frow & 7;
    const int lof0 = frow * 64 + (((q) ^ fx7) << 3);          // ks=0, elems
    const int lof1 = frow * 64 + (((4 + q) ^ fx7) << 3);      // ks=1, elems

    // prologue: tile 0 into buf0
    STAGE(lds_a0, lds_b0, 0);
    VMCNT0();
    BAR();

    // main loop: 15 iters x 2 K-tiles (computes tiles 0..29), static ping-pong
#pragma unroll 1
    for (int i = 0; i < 15; ++i) {
        const int tt = 2 * i;
        STAGE(lds_a1, lds_b1, tt + 1);
        COMPUTE(lds_a0, lds_b0);
        VMCNT0();
        BAR();
        STAGE(lds_a0, lds_b0, tt + 2);
        COMPUTE(lds_a1, lds_b1);
        VMCNT0();
        BAR();
    }
    // tail: tile 30 in buf0; stage 31 -> buf1; compute 30; compute 31
    STAGE(lds_a1, lds_b1, 31);
    COMPUTE(lds_a0, lds_b0);
    VMCNT0();
    BAR();
    COMPUTE(lds_a1, lds_b1);

    // epilogue: C/D layout col = lane&15, row = (lane>>4)*4 + reg  [m89-verified]
    const int seg = bn0 >> 11;                        // 0=A, 1=dt, 2=rawB
    const int dbase = (bn0 & 2047) + wc + (lane & 15);
    const int rowbase = bm0 + wr + (q << 2);

    if (seg == 0) {
        float bias[2];
#pragma unroll
        for (int n = 0; n < 2; n++) bias[n] = bA[dbase + n * 16];
#pragma unroll
        for (int m = 0; m < 4; m++)
#pragma unroll
            for (int n = 0; n < 2; n++)
#pragma unroll
                for (int r = 0; r < 4; r++) {
                    size_t idx = (size_t)(rowbase + m * 16 + r) * D_DIM + dbase + n * 16;
                    outA[idx] = 1.0f / (1.0f + __expf(-(acc[m][n][r] + bias[n])));
                }
    } else if (seg == 1) {
        float bias[2], sc[2];
#pragma unroll
        for (int n = 0; n < 2; n++) { bias[n] = bdt[dbase + n * 16]; sc[n] = scales[dbase + n * 16]; }
#pragma unroll
        for (int m = 0; m < 4; m++)
#pragma unroll
            for (int n = 0; n < 2; n++)
#pragma unroll
                for (int r = 0; r < 4; r++) {
                    size_t idx = (size_t)(rowbase + m * 16 + r) * D_DIM + dbase + n * 16;
                    float xx = acc[m][n][r] + bias[n];
                    float sp = xx > 0.f ? xx + log1pf(__expf(-xx)) : log1pf(__expf(xx));
                    outDT[idx] = sp * 0.1f * sc[n];
                }
    } else {
        float bias[2];
#pragma unroll
        for (int n = 0; n < 2; n++) bias[n] = bB[dbase + n * 16];
#pragma unroll
        for (int m = 0; m < 4; m++)
#pragma unroll
            for (int n = 0; n < 2; n++)
#pragma unroll
                for (int r = 0; r < 4; r++) {
                    size_t idx = (size_t)(rowbase + m * 16 + r) * D_DIM + dbase + n * 16;
                    outB[idx] = acc[m][n][r] + bias[n];
                }
    }
}

// ---------------- scan pass 1: per-chunk affine aggregates ----------------
// step map: v' = a v + bv ; x' = x + dt v'  =>  (P,R,U,W):
//   v_out = P v + U ; x_out = R v + x + W
// 2 adjacent d-channels per thread (float2 loads) — measured optimum
// (R17: f32x4 hurts via TLP loss; R18: NCH=32 hurts via pass2 doubling).
__global__ __launch_bounds__(256) void scan_pass1_kernel(
    const float* __restrict__ Aarr, const float* __restrict__ Braw,
    const float* __restrict__ dtv, float4* __restrict__ agg)
{
    int pp = blockIdx.x * 256 + threadIdx.x;    // 65536 pair-threads
    int dp = (pp & 1023) << 1;                  // d pair base
    int c = (pp >> 10) & (NCH - 1);
    int b = pp >> 14;
    size_t base = ((size_t)(b * L_SEQ + c * CHUNK)) * D_DIM + dp;
    float P0 = 1.f, R0 = 0.f, U0 = 0.f, W0 = 0.f;
    float P1 = 1.f, R1 = 0.f, U1 = 0.f, W1 = 0.f;
#pragma unroll 4
    for (int tt = 0; tt < CHUNK; tt++) {
        size_t idx = base + (size_t)tt * D_DIM;
        float2 a2  = *(const float2*)&Aarr[idx];
        float2 rb2 = *(const float2*)&Braw[idx];
        float2 dt2 = *(const float2*)&dtv[idx];
        float bv0 = rb2.x * dt2.x, bv1 = rb2.y * dt2.y;
        float da0 = dt2.x * a2.x,  da1 = dt2.y * a2.y;
        R0 = da0 * P0 + R0;  W0 = da0 * U0 + dt2.x * bv0 + W0;
        U0 = a2.x * U0 + bv0;  P0 = a2.x * P0;
        R1 = da1 * P1 + R1;  W1 = da1 * U1 + dt2.y * bv1 + W1;
        U1 = a2.y * U1 + bv1;  P1 = a2.y * P1;
    }
    int ch = ((b * NCH + c) << 11) + dp;
    agg[ch]     = make_float4(P0, R0, U0, W0);
    agg[ch + 1] = make_float4(P1, R1, U1, W1);
}

// ---------------- scan pass 2: combine chunk aggregates ----------------
__global__ __launch_bounds__(256) void scan_pass2_kernel(
    const float4* __restrict__ agg, float2* __restrict__ pre)
{
    int tid = blockIdx.x * 256 + threadIdx.x;   // 8192 channels
    int d = tid & (D_DIM - 1);
    int b = tid >> 11;
    float v = 0.f, x = 0.f;
#pragma unroll
    for (int c = 0; c < NCH; c++) {
        int i = ((b * NCH + c) << 11) + d;
        float4 g = agg[i];
        pre[i] = make_float2(v, x);             // state entering chunk c
        float vn = g.x * v + g.z;
        x = g.y * v + x + g.w;                  // uses old v
        v = vn;
    }
}

// ---------------- scan pass 3: replay chunk, write outputs in place ----------------
// A staged in xout, rawB staged in vout; overwritten in place
// (read-before-write, same element, same thread).
__global__ __launch_bounds__(256) void scan_pass3_kernel(
    const float* __restrict__ dtv, const float2* __restrict__ pre,
    float* __restrict__ xout, float* __restrict__ vout)
{
    int pp = blockIdx.x * 256 + threadIdx.x;    // 65536 pair-threads
    int dp = (pp & 1023) << 1;
    int c = (pp >> 10) & (NCH - 1);
    int b = pp >> 14;
    int ch = ((b * NCH + c) << 11) + dp;
    float4 pv = *(const float4*)&pre[ch];       // {v0,x0,v1,x1}
    float v0 = pv.x, x0 = pv.y, v1 = pv.z, x1 = pv.w;
    size_t base = ((size_t)(b * L_SEQ + c * CHUNK)) * D_DIM + dp;
#pragma unroll 4
    for (int tt = 0; tt < CHUNK; tt++) {
        size_t idx = base + (size_t)tt * D_DIM;
        float2 a2  = *(const float2*)&xout[idx];   // A (staged)
        float2 rb2 = *(const float2*)&vout[idx];   // rawB (staged)
        float2 dt2 = *(const float2*)&dtv[idx];
        v0 = a2.x * v0 + rb2.x * dt2.x;
        x0 = x0 + v0 * dt2.x;
        v1 = a2.y * v1 + rb2.y * dt2.y;
        x1 = x1 + v1 * dt2.y;
        *(float2*)&vout[idx] = make_float2(v0, v1);
        *(float2*)&xout[idx] = make_float2(x0, x1);
    }
}

extern "C" void kernel_launch(void* const* d_in, const int* in_sizes, int n_in,
                              void* d_out, int out_size, void* d_ws, size_t ws_size,
                              hipStream_t stream) {
    // inputs: 0:x 1:v 2:force 3:WA 4:bA 5:WB 6:bB 7:Wdt 8:bdt 9:scales
    const float* force  = (const float*)d_in[2];
    const float* WA     = (const float*)d_in[3];
    const float* bA     = (const float*)d_in[4];
    const float* WB     = (const float*)d_in[5];
    const float* bB     = (const float*)d_in[6];
    const float* Wdt    = (const float*)d_in[7];
    const float* bdt    = (const float*)d_in[8];
    const float* scales = (const float*)d_in[9];

    float* xout = (float*)d_out;                          // x_seq [8192*2048]
    float* vout = xout + (size_t)M_ROWS * D_DIM;          // v_seq

    // ws layout (123 MiB): R1 layout
    char* ws = (char*)d_ws;
    bf16_t* fbf = (bf16_t*)ws;                                     // 32 MB
    bf16_t* wt  = (bf16_t*)(ws + (size_t)33554432);                // 24 MB
    float*  dtv = (float*)(ws + (size_t)33554432 + 25165824);      // 64 MB
    float4* agg = (float4*)(ws + (size_t)33554432 + 25165824 + 67108864); // 2 MB
    float2* pre = (float2*)(ws + (size_t)33554432 + 25165824 + 67108864 + 2097152); // 1 MB

    // 1) force -> bf16
    {
        int n8 = M_ROWS * D_DIM / 8;
        cvt_bf16_kernel<<<n8 / 256, 256, 0, stream>>>(force, fbf, n8);
    }
    // 2) transpose + convert weights into concat [6144][2048]: A | dt | B
    {
        dim3 grid(D_DIM / 32, D_DIM / 32, 3), block(32, 8);
        transpose_w_kernel<<<grid, block, 0, stream>>>(WA, Wdt, WB, wt);
    }
    // 3) fused GEMM + activations (BK=64, 2-phase dbuf, 8 waves / 128^2)
    {
        dim3 grid(M_ROWS / 128, NT_COLS / 128);   // (64, 48)
        gemm_fused_kernel<<<grid, 512, 0, stream>>>(fbf, wt, bA, bdt, bB, scales,
                                                    xout, dtv, vout);
    }
    // 4-6) chunked associative scan (NCH=16, 2 channels per thread)
    scan_pass1_kernel<<<(B_SZ * NCH * D_DIM / 2) / 256, 256, 0, stream>>>(xout, vout, dtv, agg);
    scan_pass2_kernel<<<(B_SZ * D_DIM) / 256, 256, 0, stream>>>(agg, pre);
    scan_pass3_kernel<<<(B_SZ * NCH * D_DIM / 2) / 256, 256, 0, stream>>>(dtv, pre, xout, vout);
}